// Round 10
// baseline (512.053 us; speedup 1.0000x reference)
//
#include <hip/hip_runtime.h>
#include <stdint.h>

#define ROWS 8192   // B*N
#define N_ 512

typedef __attribute__((ext_vector_type(4))) float f32x4;
typedef __attribute__((ext_vector_type(8))) short s16x8;
typedef __attribute__((ext_vector_type(4))) short s16x4;
typedef __attribute__((ext_vector_type(4))) unsigned short u16x4;
typedef __attribute__((ext_vector_type(8))) unsigned short u16x8;

__device__ __forceinline__ float bf2f(unsigned short h){
  union { unsigned int u; float f; } v; v.u = ((unsigned int)h) << 16; return v.f;
}
__device__ __forceinline__ unsigned short f2bf(float f){
  union { float f; unsigned int u; } v; v.f = f;
  unsigned int r = v.u + 0x7FFFu + ((v.u >> 16) & 1u);
  return (unsigned short)(r >> 16);
}
__device__ __forceinline__ float sigm(float x){ return 1.f / (1.f + __expf(-x)); }
__device__ __forceinline__ unsigned cvtpk(float lo, float hi){
  unsigned r;
  asm("v_cvt_pk_bf16_f32 %0, %1, %2" : "=v"(r) : "v"(lo), "v"(hi));
  return r;
}
// async global->LDS, 16B per lane; dest must be linear (wave base + lane*16)
__device__ __forceinline__ void gload16(const void* g, void* l){
  __builtin_amdgcn_global_load_lds(
    (const __attribute__((address_space(1))) void*)g,
    (__attribute__((address_space(3))) void*)l, 16, 0, 0);
}

// ---------------- weight prep ----------------
__global__ void k_transpose_cvt(const float* __restrict__ in, unsigned short* __restrict__ out,
                                int R, int C){
  __shared__ float t[32][33];
  int c0 = blockIdx.x*32, r0 = blockIdx.y*32;
  int tx = threadIdx.x & 31, ty = threadIdx.x >> 5;
  #pragma unroll
  for(int i=0;i<32;i+=8) t[ty+i][tx] = in[(size_t)(r0+ty+i)*C + c0+tx];
  __syncthreads();
  #pragma unroll
  for(int i=0;i<32;i+=8) out[(size_t)(c0+ty+i)*R + r0+tx] = f2bf(t[tx][ty+i]);
}

__global__ void k_cvt(const float* __restrict__ in, unsigned short* __restrict__ out, int n){
  int i = blockIdx.x*256 + threadIdx.x;
  if(i < n) out[i] = f2bf(in[i]);
}

// ---------------- LayerNorm (rows of 512) ----------------
template<int OUTF32>
__global__ void k_ln(const float* __restrict__ x, const float* __restrict__ gw,
                     const float* __restrict__ bw, void* __restrict__ outp){
  const int row = blockIdx.x*4 + (threadIdx.x >> 6);
  const int lane = threadIdx.x & 63;
  const f32x4* xr = (const f32x4*)(x + (size_t)row*512);
  f32x4 v0 = xr[lane], v1 = xr[lane + 64];
  float s  = v0[0]+v0[1]+v0[2]+v0[3] + v1[0]+v1[1]+v1[2]+v1[3];
  float s2 = v0[0]*v0[0]+v0[1]*v0[1]+v0[2]*v0[2]+v0[3]*v0[3]
           + v1[0]*v1[0]+v1[1]*v1[1]+v1[2]*v1[2]+v1[3]*v1[3];
  #pragma unroll
  for(int off=1; off<64; off<<=1){ s += __shfl_xor(s, off); s2 += __shfl_xor(s2, off); }
  float mean = s * (1.f/512.f);
  float inv = rsqrtf(s2*(1.f/512.f) - mean*mean + 1e-5f);
  const f32x4* gv = (const f32x4*)gw; const f32x4* bv = (const f32x4*)bw;
  f32x4 g0 = gv[lane], g1 = gv[lane+64], b0 = bv[lane], b1 = bv[lane+64];
  f32x4 o0, o1;
  #pragma unroll
  for(int e=0;e<4;e++){ o0[e] = (v0[e]-mean)*inv*g0[e] + b0[e];
                        o1[e] = (v1[e]-mean)*inv*g1[e] + b1[e]; }
  if(OUTF32){
    f32x4* op = (f32x4*)((float*)outp + (size_t)row*512);
    op[lane] = o0; op[lane+64] = o1;
  } else {
    unsigned short* ob = (unsigned short*)outp + (size_t)row*512;
    s16x4 h0, h1;
    #pragma unroll
    for(int e=0;e<4;e++){ h0[e] = (short)f2bf(o0[e]); h1[e] = (short)f2bf(o1[e]); }
    *(s16x4*)(ob + lane*4) = h0;
    *(s16x4*)(ob + 256 + lane*4) = h1;
  }
}

// ---------------- GEMM: C[M,N] = A[M,K] @ Bt[N,K]^T, bf16 in, fp32 acc ----------------
// EPI: 0=store bf16; 1=+bias,swish->bf16; 2=+bias,*0.5,+res->f32; 3=+res->f32;
//      4=+bias->bf16; 5=+bias,+res->f32; 6=qkv special (cols<1024 bf16, cols>=1024 -> vt transposed)
template<int EPI>
__global__ __launch_bounds__(256, 2)
void k_gemm(const unsigned short* __restrict__ A, const unsigned short* __restrict__ Bt,
            const float* __restrict__ bias, const float* __restrict__ res,
            void* __restrict__ outp, unsigned short* __restrict__ vt, int M, int N, int K){
  __shared__ alignas(16) unsigned short As[128*64];
  __shared__ alignas(16) unsigned short Bs[128*64];
  const int tid = threadIdx.x, lane = tid & 63, wave = tid >> 6;
  // bijective XCD swizzle (m204)
  const int nwg = gridDim.x * gridDim.y;
  int orig = blockIdx.x + gridDim.x * blockIdx.y;
  int q8 = nwg >> 3, r8 = nwg & 7, xcd = orig & 7, idx = orig >> 3;
  int wg = (xcd < r8 ? xcd * (q8 + 1) : r8 * (q8 + 1) + (xcd - r8) * q8) + idx;
  const int m0 = (wg / gridDim.x) * 128, n0 = (wg % gridDim.x) * 128;
  const int wm = (wave >> 1) * 64, wn = (wave & 1) * 64;
  f32x4 acc[4][4];
  #pragma unroll
  for(int a=0;a<4;a++)
    #pragma unroll
    for(int b=0;b<4;b++) acc[a][b] = (f32x4){0.f,0.f,0.f,0.f};

  for(int kt = 0; kt < K; kt += 64){
    // async stage: linear LDS dest (wave base + lane*16), pre-swizzled global source
    #pragma unroll
    for(int i=0;i<4;i++){
      int flat = i*256 + tid;
      int r = flat >> 3;
      int cs = ((flat & 7) ^ (r & 7)) << 3;     // swizzled source chunk (elements)
      gload16(A  + (size_t)(m0 + r)*K + kt + cs, &As[flat*8]);
      gload16(Bt + (size_t)(n0 + r)*K + kt + cs, &Bs[flat*8]);
    }
    __syncthreads();
    #pragma unroll
    for(int ks=0; ks<2; ks++){
      s16x8 af[4], bfr[4];
      #pragma unroll
      for(int mi=0;mi<4;mi++){
        int row = wm + mi*16 + (lane & 15);
        int ch = (ks*4 + (lane >> 4)) ^ (row & 7);
        af[mi] = *(const s16x8*)(&As[row*64 + ch*8]);
      }
      #pragma unroll
      for(int ni=0;ni<4;ni++){
        int row = wn + ni*16 + (lane & 15);
        int ch = (ks*4 + (lane >> 4)) ^ (row & 7);
        bfr[ni] = *(const s16x8*)(&Bs[row*64 + ch*8]);
      }
      #pragma unroll
      for(int mi=0;mi<4;mi++)
        #pragma unroll
        for(int ni=0;ni<4;ni++)
          acc[mi][ni] = __builtin_amdgcn_mfma_f32_16x16x32_bf16(af[mi], bfr[ni], acc[mi][ni], 0, 0, 0);
    }
    __syncthreads();
  }
  const int rb = (lane >> 4) * 4, cb = lane & 15;
  #pragma unroll
  for(int mi=0;mi<4;mi++){
    #pragma unroll
    for(int ni=0;ni<4;ni++){
      int col = n0 + wn + ni*16 + cb;
      int rowbase = m0 + wm + mi*16 + rb;
      if(EPI==6 && col >= 1024){
        // V columns: write transposed to vt[(b*8+h)*64+d][n] = vt[b*512+col-1024][n]
        u16x4 tv;
        #pragma unroll
        for(int r=0;r<4;r++) tv[r] = f2bf(acc[mi][ni][r]);
        int bb = rowbase >> 9, n = rowbase & 511;
        *(u16x4*)(vt + (((size_t)(bb*512 + col - 1024)) << 9) + n) = tv;
      } else {
        #pragma unroll
        for(int r=0;r<4;r++){
          int row = rowbase + r;
          float v = acc[mi][ni][r];
          if(EPI==1||EPI==2||EPI==4||EPI==5) v += bias[col];
          if(EPI==2) v = 0.5f*v + res[(size_t)row*N + col];
          if(EPI==3||EPI==5) v += res[(size_t)row*N + col];
          if(EPI==1) v = v * sigm(v);
          if(EPI==0||EPI==1||EPI==4||EPI==6) ((unsigned short*)outp)[(size_t)row*N + col] = f2bf(v);
          else                               ((float*)outp)[(size_t)row*N + col] = v;
        }
      }
    }
  }
}

// ---------------- fused attention, online softmax, NO LDS (K and V from L2) ----
// grid (4 q-tiles of 128, H=8, B=16), 8 waves; wave w owns q rows n0w..n0w+15.
// R9 showed 72us flat despite halving MFMA work: latency-bound at 38% occupancy
// (64KB LDS -> 2 blocks/CU). K per (b,h) is 64KB, read by 4 blocks x 8 waves ->
// L2-resident; read it per-lane from global like V. No LDS -> 4 blocks/CU
// (32 waves, 100% slots), no staging barrier, no ds_read, no bank conflicts.
__global__ __launch_bounds__(512, 2)
void k_attn(const unsigned short* __restrict__ qkv, const unsigned short* __restrict__ vt,
            const unsigned short* __restrict__ emb, unsigned short* __restrict__ outb){
  const int tid = threadIdx.x, lane = tid & 63, w = tid >> 6;
  const int q0 = blockIdx.x * 128, h = blockIdx.y, b = blockIdx.z;
  const int j = lane & 15, g = lane >> 4;
  const int n0w = q0 + w*16;
  const size_t qkvbase = (size_t)b*N_*1536;
  const unsigned short* kbase = qkv + qkvbase + 512 + h*64;   // K row stride 1536

  // Q fragment: lane (j,g) holds Q[n0w+j][ks*32+g*8+e]
  s16x8 qf[2];
  #pragma unroll
  for(int ks=0;ks<2;ks++)
    qf[ks] = *(const s16x8*)(qkv + qkvbase + (size_t)(n0w + j)*1536 + h*64 + ks*32 + g*8);

  const float C2 = 0.125f * 1.4426950408889634f;

  // band init: pa1 = Paux of virtual rt=-1 (rows n0w+513+j)
  f32x4 pa1 = {0.f,0.f,0.f,0.f};
  #pragma unroll
  for(int ks=0;ks<2;ks++){
    s16x8 e1 = *(const s16x8*)(emb + (size_t)(n0w + 513 + j)*64 + ks*32 + g*8);
    pa1 = __builtin_amdgcn_mfma_f32_16x16x32_bf16(e1, qf[ks], pa1, 0,0,0);
  }

  float m = -1e30f, l = 0.f;
  f32x4 o[4];
  #pragma unroll
  for(int dt=0;dt<4;dt++) o[dt] = (f32x4){0.f,0.f,0.f,0.f};
  const unsigned short* vbase = vt + (((size_t)(b*8 + h)) << 15);  // *64*512
  const int srcA = j + ((g & 1) << 5);
  const int srcB = srcA + 16;
  const bool hi = (g >= 2);

  #pragma unroll
  for(int rts=0; rts<16; rts++){
    f32x4 scs[2];
    #pragma unroll
    for(int sub=0; sub<2; sub++){
      const int rt = rts*2 + sub;
      const int cb = n0w - rt*16 + 512;
      f32x4 s   = {0.f,0.f,0.f,0.f};
      f32x4 pa0 = {0.f,0.f,0.f,0.f};
      #pragma unroll
      for(int ks=0;ks<2;ks++){
        s16x8 kf = *(const s16x8*)(kbase + (size_t)(rt*16 + j)*1536 + ks*32 + g*8);
        s = __builtin_amdgcn_mfma_f32_16x16x32_bf16(kf, qf[ks], s, 0,0,0);
        s16x8 e0 = *(const s16x8*)(emb + (size_t)(cb - 15 + j)*64 + ks*32 + g*8);
        pa0 = __builtin_amdgcn_mfma_f32_16x16x32_bf16(e0, qf[ks], pa0, 0,0,0);
      }
      #pragma unroll
      for(int reg=0;reg<4;reg++){
        int elem = (j + 3 - reg) & 3;
        float s0 = (elem & 2) ? ((elem & 1) ? pa0[3] : pa0[2]) : ((elem & 1) ? pa0[1] : pa0[0]);
        float s1 = (elem & 2) ? ((elem & 1) ? pa1[3] : pa1[2]) : ((elem & 1) ? pa1[1] : pa1[0]);
        int mm = j + 15 - g*4 - reg;
        int src = j + (((mm & 15) >> 2) << 4);
        float v0 = __shfl(s0, src);
        float v1 = __shfl(s1, src);
        scs[sub][reg] = s[reg] + (mm < 16 ? v0 : v1);
      }
      pa1 = pa0;
    }
    // group max (per q-row j; uniform across the 4 lane-groups after xor reduce)
    float tmax = fmaxf(fmaxf(fmaxf(scs[0][0], scs[0][1]), fmaxf(scs[0][2], scs[0][3])),
                       fmaxf(fmaxf(scs[1][0], scs[1][1]), fmaxf(scs[1][2], scs[1][3])));
    tmax = fmaxf(tmax, __shfl_xor(tmax, 16));
    tmax = fmaxf(tmax, __shfl_xor(tmax, 32));
    if(__any(tmax > m + 48.f)){
      float mn = fmaxf(m, tmax);
      float f = exp2f((m - mn)*C2);
      l *= f;
      #pragma unroll
      for(int reg=0;reg<4;reg++){
        float fr = __shfl(f, (g<<2) + reg);
        #pragma unroll
        for(int dt=0;dt<4;dt++) o[dt][reg] *= fr;
      }
      m = mn;
    }
    const float mc = m * C2;
    unsigned wp[4];
    #pragma unroll
    for(int sub=0; sub<2; sub++){
      float p0 = exp2f(fmaf(scs[sub][0], C2, -mc));
      float p1 = exp2f(fmaf(scs[sub][1], C2, -mc));
      float p2 = exp2f(fmaf(scs[sub][2], C2, -mc));
      float p3 = exp2f(fmaf(scs[sub][3], C2, -mc));
      l += (p0 + p1) + (p2 + p3);
      wp[sub*2]   = cvtpk(p0, p1);
      wp[sub*2+1] = cvtpk(p2, p3);
    }
    // build PV A-frag via cross-lane gather of packed P
    unsigned a0 = __shfl(wp[0], srcA);
    unsigned a1 = __shfl(wp[1], srcA);
    unsigned a2 = __shfl(wp[0], srcB);
    unsigned a3 = __shfl(wp[1], srcB);
    unsigned b0 = __shfl(wp[2], srcA);
    unsigned b1 = __shfl(wp[3], srcA);
    unsigned b2 = __shfl(wp[2], srcB);
    unsigned b3 = __shfl(wp[3], srcB);
    union { unsigned u[4]; s16x8 v; } pu;
    pu.u[0] = hi ? b0 : a0;
    pu.u[1] = hi ? b1 : a1;
    pu.u[2] = hi ? b2 : a2;
    pu.u[3] = hi ? b3 : a3;
    #pragma unroll
    for(int dt=0;dt<4;dt++){
      int d = dt*16 + j;
      s16x8 vf = *(const s16x8*)(vbase + (size_t)d*512 + rts*32 + g*8);
      o[dt] = __builtin_amdgcn_mfma_f32_16x16x32_bf16(pu.v, vf, o[dt], 0,0,0);
    }
  }
  l += __shfl_xor(l, 16);
  l += __shfl_xor(l, 32);
  float inv = 1.f / l;
  // epilogue: fold 1/sum, write
  #pragma unroll
  for(int reg=0;reg<4;reg++){
    float invq = __shfl(inv, (g<<2) + reg);
    int tok = n0w + (g<<2) + reg;
    #pragma unroll
    for(int dt=0;dt<4;dt++)
      outb[(size_t)(b*N_ + tok)*512 + h*64 + dt*16 + j] = f2bf(o[dt][reg] * invq);
  }
}

// ---------------- GLU ----------------
__global__ void k_glu(const unsigned short* __restrict__ hid, unsigned short* __restrict__ outp){
  size_t i = (size_t)blockIdx.x*256 + threadIdx.x;   // chunk of 8
  int row = (int)(i >> 7), cc = (int)(i & 127);
  u16x8 a  = *(const u16x8*)(hid + (size_t)row*2048 + cc*8);
  u16x8 gt = *(const u16x8*)(hid + (size_t)row*2048 + 1024 + cc*8);
  u16x8 o;
  #pragma unroll
  for(int e=0;e<8;e++){
    float av = bf2f(a[e]), gv = bf2f(gt[e]);
    o[e] = f2bf(av * sigm(gv));
  }
  *(u16x8*)(outp + (size_t)row*1024 + cc*8) = o;
}

// ---------------- depthwise conv 31 + BN + swish ----------------
__global__ __launch_bounds__(256, 2)
void k_dwconv(const unsigned short* __restrict__ gin, const float* __restrict__ dww,
              const float* __restrict__ dwb, const float* __restrict__ bng,
              const float* __restrict__ bnb, const float* __restrict__ bnm,
              const float* __restrict__ bnv, unsigned short* __restrict__ outp){
  __shared__ unsigned short gl[94][136];
  __shared__ float wl[31][128];
  const int c0 = blockIdx.x*128, n0 = blockIdx.y*64, b = blockIdx.z;
  const int tid = threadIdx.x;
  for(int i=0;i<6;i++){
    int flat = i*256 + tid;
    if(flat < 94*16){
      int r = flat >> 4, c = flat & 15;
      int n = n0 - 15 + r;
      u16x8 v = {0,0,0,0,0,0,0,0};
      if(n >= 0 && n < 512) v = *(const u16x8*)(gin + (size_t)(b*512 + n)*1024 + c0 + c*8);
      *(u16x8*)(&gl[r][c*8]) = v;
    }
  }
  for(int i=0;i<16;i++){
    int flat = i*256 + tid;
    if(flat < 31*128){
      int t = flat >> 7, cc = flat & 127;
      wl[t][cc] = dww[(size_t)(c0 + cc)*31 + t];
    }
  }
  __syncthreads();
  const int tc = tid & 31, tn = tid >> 5;
  f32x4 acc[8];
  #pragma unroll
  for(int nn=0;nn<8;nn++) acc[nn] = (f32x4){0.f,0.f,0.f,0.f};
  for(int t=0;t<31;t++){
    f32x4 wv = *(const f32x4*)(&wl[t][tc*4]);
    #pragma unroll
    for(int nn=0;nn<8;nn++){
      s16x4 gv = *(const s16x4*)(&gl[tn*8 + nn + t][tc*4]);
      f32x4 g4 = { bf2f((unsigned short)gv[0]), bf2f((unsigned short)gv[1]),
                   bf2f((unsigned short)gv[2]), bf2f((unsigned short)gv[3]) };
      acc[nn] += g4 * wv;
    }
  }
  #pragma unroll
  for(int e=0;e<4;e++){
    int c = c0 + tc*4 + e;
    float s  = bng[c] * rsqrtf(bnv[c] + 1e-5f);
    float sh = bnb[c] - bnm[c]*s;
    float db = dwb[c];
    #pragma unroll
    for(int nn=0;nn<8;nn++){
      float v = (acc[nn][e] + db)*s + sh;
      v = v * sigm(v);
      outp[(size_t)(b*512 + n0 + tn*8 + nn)*1024 + c] = f2bf(v);
    }
  }
}

// ---------------- launch ----------------
extern "C" void kernel_launch(void* const* d_in, const int* in_sizes, int n_in,
                              void* d_out, int out_size, void* d_ws, size_t ws_size,
                              hipStream_t stream){
  const float* x        = (const float*)d_in[0];
  const float* ff1_ln_g = (const float*)d_in[1];
  const float* ff1_ln_b = (const float*)d_in[2];
  const float* ff1_w1   = (const float*)d_in[3];
  const float* ff1_b1   = (const float*)d_in[4];
  const float* ff1_w2   = (const float*)d_in[5];
  const float* ff1_b2   = (const float*)d_in[6];
  const float* attn_ln_g= (const float*)d_in[7];
  const float* attn_ln_b= (const float*)d_in[8];
  const float* qkv_w    = (const float*)d_in[9];
  const float* out_w    = (const float*)d_in[10];
  const float* rel_emb  = (const float*)d_in[11];
  const float* conv_ln_g= (const float*)d_in[12];
  const float* conv_ln_b= (const float*)d_in[13];
  const float* pw1_w    = (const float*)d_in[14];
  const float* pw1_b    = (const float*)d_in[15];
  const float* dw_w     = (const float*)d_in[16];
  const float* dw_b     = (const float*)d_in[17];
  const float* bn_g     = (const float*)d_in[18];
  const float* bn_b     = (const float*)d_in[19];
  const float* bn_mean  = (const float*)d_in[20];
  const float* bn_var   = (const float*)d_in[21];
  const float* pw2_w    = (const float*)d_in[22];
  const float* pw2_b    = (const float*)d_in[23];
  const float* ff2_ln_g = (const float*)d_in[24];
  const float* ff2_ln_b = (const float*)d_in[25];
  const float* ff2_w1   = (const float*)d_in[26];
  const float* ff2_b1   = (const float*)d_in[27];
  const float* ff2_w2   = (const float*)d_in[28];
  const float* ff2_b2   = (const float*)d_in[29];
  const float* post_ln_g= (const float*)d_in[30];
  const float* post_ln_b= (const float*)d_in[31];
  (void)in_sizes; (void)n_in; (void)out_size; (void)ws_size;

  char* ws = (char*)d_ws;
  size_t off = 0;
  auto alloc = [&](size_t bytes)->char*{ char* p = ws + off; off += (bytes + 255) & ~(size_t)255; return p; };
  float*          res  = (float*)         alloc((size_t)ROWS*512*4);
  unsigned short* hbuf = (unsigned short*)alloc((size_t)ROWS*512*2);
  unsigned short* hid  = (unsigned short*)alloc((size_t)ROWS*2048*2);
  unsigned short* qkvb = (unsigned short*)alloc((size_t)ROWS*1536*2);
  unsigned short* glub = (unsigned short*)alloc((size_t)ROWS*1024*2);
  unsigned short* attnout = glub;   // alias: attn_out consumed before GLU is written
  unsigned short* dwout   = qkvb;   // alias: qkv consumed before dwconv output written
  unsigned short* vtb     = hid;    // alias: hid free between FF1 and conv module
  unsigned short* w1t  = (unsigned short*)alloc((size_t)2048*512*2);
  unsigned short* w2t  = (unsigned short*)alloc((size_t)2048*512*2);
  unsigned short* qkvt = (unsigned short*)alloc((size_t)1536*512*2);
  unsigned short* outt = (unsigned short*)alloc((size_t)512*512*2);
  unsigned short* pw1c = (unsigned short*)alloc((size_t)2048*512*2);
  unsigned short* pw2c = (unsigned short*)alloc((size_t)512*1024*2);
  unsigned short* f2w1t= (unsigned short*)alloc((size_t)2048*512*2);
  unsigned short* f2w2t= (unsigned short*)alloc((size_t)2048*512*2);
  unsigned short* rele = (unsigned short*)alloc((size_t)1025*64*2);

  // weight prep (all -> bf16 [N][K])
  k_transpose_cvt<<<dim3(64, 16), 256, 0, stream>>>(ff1_w1, w1t, 512, 2048);
  k_transpose_cvt<<<dim3(16, 64), 256, 0, stream>>>(ff1_w2, w2t, 2048, 512);
  k_transpose_cvt<<<dim3(48, 16), 256, 0, stream>>>(qkv_w, qkvt, 512, 1536);
  k_transpose_cvt<<<dim3(16, 16), 256, 0, stream>>>(out_w, outt, 512, 512);
  k_transpose_cvt<<<dim3(64, 16), 256, 0, stream>>>(ff2_w1, f2w1t, 512, 2048);
  k_transpose_cvt<<<dim3(16, 64), 256, 0, stream>>>(ff2_w2, f2w2t, 2048, 512);
  k_cvt<<<2048*512/256, 256, 0, stream>>>(pw1_w, pw1c, 2048*512);
  k_cvt<<<512*1024/256, 256, 0, stream>>>(pw2_w, pw2c, 512*1024);
  k_cvt<<<(1025*64+255)/256, 256, 0, stream>>>(rel_emb, rele, 1025*64);

  // FF1 (x + 0.5*ff(x))
  k_ln<0><<<ROWS/4, 256, 0, stream>>>(x, ff1_ln_g, ff1_ln_b, hbuf);
  k_gemm<1><<<dim3(16, 64), 256, 0, stream>>>(hbuf, w1t, ff1_b1, nullptr, hid, nullptr, ROWS, 2048, 512);
  k_gemm<2><<<dim3(4, 64), 256, 0, stream>>>(hid, w2t, ff1_b2, x, res, nullptr, ROWS, 512, 2048);
  // attention
  k_ln<0><<<ROWS/4, 256, 0, stream>>>(res, attn_ln_g, attn_ln_b, hbuf);
  k_gemm<6><<<dim3(12, 64), 256, 0, stream>>>(hbuf, qkvt, nullptr, nullptr, qkvb, vtb, ROWS, 1536, 512);
  k_attn<<<dim3(4, 8, 16), 512, 0, stream>>>(qkvb, vtb, rele, attnout);
  k_gemm<3><<<dim3(4, 64), 256, 0, stream>>>(attnout, outt, nullptr, res, res, nullptr, ROWS, 512, 512);
  // conv module
  k_ln<0><<<ROWS/4, 256, 0, stream>>>(res, conv_ln_g, conv_ln_b, hbuf);
  k_gemm<4><<<dim3(16, 64), 256, 0, stream>>>(hbuf, pw1c, pw1_b, nullptr, hid, nullptr, ROWS, 2048, 512);
  k_glu<<<ROWS*128/256, 256, 0, stream>>>(hid, glub);
  k_dwconv<<<dim3(8, 8, 16), 256, 0, stream>>>(glub, dw_w, dw_b, bn_g, bn_b, bn_mean, bn_var, dwout);
  k_gemm<5><<<dim3(4, 64), 256, 0, stream>>>(dwout, pw2c, pw2_b, res, res, nullptr, ROWS, 512, 1024);
  // FF2
  k_ln<0><<<ROWS/4, 256, 0, stream>>>(res, ff2_ln_g, ff2_ln_b, hbuf);
  k_gemm<1><<<dim3(16, 64), 256, 0, stream>>>(hbuf, f2w1t, ff2_b1, nullptr, hid, nullptr, ROWS, 2048, 512);
  k_gemm<2><<<dim3(4, 64), 256, 0, stream>>>(hid, f2w2t, ff2_b2, res, res, nullptr, ROWS, 512, 2048);
  // post-norm -> fp32 output
  k_ln<1><<<ROWS/4, 256, 0, stream>>>(res, post_ln_g, post_ln_b, d_out);
}

// Round 11
// 462.445 us; speedup vs baseline: 1.1073x; 1.1073x over previous
//
#include <hip/hip_runtime.h>
#include <stdint.h>

#define ROWS 8192   // B*N
#define N_ 512

typedef __attribute__((ext_vector_type(4))) float f32x4;
typedef __attribute__((ext_vector_type(8))) short s16x8;
typedef __attribute__((ext_vector_type(4))) short s16x4;
typedef __attribute__((ext_vector_type(4))) unsigned short u16x4;
typedef __attribute__((ext_vector_type(8))) unsigned short u16x8;

__device__ __forceinline__ float bf2f(unsigned short h){
  union { unsigned int u; float f; } v; v.u = ((unsigned int)h) << 16; return v.f;
}
__device__ __forceinline__ unsigned short f2bf(float f){
  union { float f; unsigned int u; } v; v.f = f;
  unsigned int r = v.u + 0x7FFFu + ((v.u >> 16) & 1u);
  return (unsigned short)(r >> 16);
}
__device__ __forceinline__ float sigm(float x){ return 1.f / (1.f + __expf(-x)); }
__device__ __forceinline__ unsigned cvtpk(float lo, float hi){
  unsigned r;
  asm("v_cvt_pk_bf16_f32 %0, %1, %2" : "=v"(r) : "v"(lo), "v"(hi));
  return r;
}
// async global->LDS, 16B per lane; dest must be linear (wave base + lane*16)
__device__ __forceinline__ void gload16(const void* g, void* l){
  __builtin_amdgcn_global_load_lds(
    (const __attribute__((address_space(1))) void*)g,
    (__attribute__((address_space(3))) void*)l, 16, 0, 0);
}

// ---------------- weight prep ----------------
__global__ void k_transpose_cvt(const float* __restrict__ in, unsigned short* __restrict__ out,
                                int R, int C){
  __shared__ float t[32][33];
  int c0 = blockIdx.x*32, r0 = blockIdx.y*32;
  int tx = threadIdx.x & 31, ty = threadIdx.x >> 5;
  #pragma unroll
  for(int i=0;i<32;i+=8) t[ty+i][tx] = in[(size_t)(r0+ty+i)*C + c0+tx];
  __syncthreads();
  #pragma unroll
  for(int i=0;i<32;i+=8) out[(size_t)(c0+ty+i)*R + r0+tx] = f2bf(t[tx][ty+i]);
}

__global__ void k_cvt(const float* __restrict__ in, unsigned short* __restrict__ out, int n){
  int i = blockIdx.x*256 + threadIdx.x;
  if(i < n) out[i] = f2bf(in[i]);
}

// ---------------- LayerNorm (rows of 512) ----------------
template<int OUTF32>
__global__ void k_ln(const float* __restrict__ x, const float* __restrict__ gw,
                     const float* __restrict__ bw, void* __restrict__ outp){
  const int row = blockIdx.x*4 + (threadIdx.x >> 6);
  const int lane = threadIdx.x & 63;
  const f32x4* xr = (const f32x4*)(x + (size_t)row*512);
  f32x4 v0 = xr[lane], v1 = xr[lane + 64];
  float s  = v0[0]+v0[1]+v0[2]+v0[3] + v1[0]+v1[1]+v1[2]+v1[3];
  float s2 = v0[0]*v0[0]+v0[1]*v0[1]+v0[2]*v0[2]+v0[3]*v0[3]
           + v1[0]*v1[0]+v1[1]*v1[1]+v1[2]*v1[2]+v1[3]*v1[3];
  #pragma unroll
  for(int off=1; off<64; off<<=1){ s += __shfl_xor(s, off); s2 += __shfl_xor(s2, off); }
  float mean = s * (1.f/512.f);
  float inv = rsqrtf(s2*(1.f/512.f) - mean*mean + 1e-5f);
  const f32x4* gv = (const f32x4*)gw; const f32x4* bv = (const f32x4*)bw;
  f32x4 g0 = gv[lane], g1 = gv[lane+64], b0 = bv[lane], b1 = bv[lane+64];
  f32x4 o0, o1;
  #pragma unroll
  for(int e=0;e<4;e++){ o0[e] = (v0[e]-mean)*inv*g0[e] + b0[e];
                        o1[e] = (v1[e]-mean)*inv*g1[e] + b1[e]; }
  if(OUTF32){
    f32x4* op = (f32x4*)((float*)outp + (size_t)row*512);
    op[lane] = o0; op[lane+64] = o1;
  } else {
    unsigned short* ob = (unsigned short*)outp + (size_t)row*512;
    s16x4 h0, h1;
    #pragma unroll
    for(int e=0;e<4;e++){ h0[e] = (short)f2bf(o0[e]); h1[e] = (short)f2bf(o1[e]); }
    *(s16x4*)(ob + lane*4) = h0;
    *(s16x4*)(ob + 256 + lane*4) = h1;
  }
}

// ---------------- GEMM 128x128: C[M,N] = A[M,K] @ Bt[N,K]^T, bf16 in, fp32 acc ----
// EPI: 0=store bf16; 1=+bias,swish->bf16; 2=+bias,*0.5,+res->f32; 3=+res->f32;
//      4=+bias->bf16; 5=+bias,+res->f32; 6=qkv special (cols<1024 bf16, cols>=1024 -> vt transposed)
template<int EPI>
__global__ __launch_bounds__(256, 2)
void k_gemm(const unsigned short* __restrict__ A, const unsigned short* __restrict__ Bt,
            const float* __restrict__ bias, const float* __restrict__ res,
            void* __restrict__ outp, unsigned short* __restrict__ vt, int M, int N, int K){
  __shared__ alignas(16) unsigned short As[128*64];
  __shared__ alignas(16) unsigned short Bs[128*64];
  const int tid = threadIdx.x, lane = tid & 63, wave = tid >> 6;
  // bijective XCD swizzle (m204)
  const int nwg = gridDim.x * gridDim.y;
  int orig = blockIdx.x + gridDim.x * blockIdx.y;
  int q8 = nwg >> 3, r8 = nwg & 7, xcd = orig & 7, idx = orig >> 3;
  int wg = (xcd < r8 ? xcd * (q8 + 1) : r8 * (q8 + 1) + (xcd - r8) * q8) + idx;
  const int m0 = (wg / gridDim.x) * 128, n0 = (wg % gridDim.x) * 128;
  const int wm = (wave >> 1) * 64, wn = (wave & 1) * 64;
  f32x4 acc[4][4];
  #pragma unroll
  for(int a=0;a<4;a++)
    #pragma unroll
    for(int b=0;b<4;b++) acc[a][b] = (f32x4){0.f,0.f,0.f,0.f};

  for(int kt = 0; kt < K; kt += 64){
    #pragma unroll
    for(int i=0;i<4;i++){
      int flat = i*256 + tid;
      int r = flat >> 3;
      int cs = ((flat & 7) ^ (r & 7)) << 3;     // swizzled source chunk (elements)
      gload16(A  + (size_t)(m0 + r)*K + kt + cs, &As[flat*8]);
      gload16(Bt + (size_t)(n0 + r)*K + kt + cs, &Bs[flat*8]);
    }
    __syncthreads();
    #pragma unroll
    for(int ks=0; ks<2; ks++){
      s16x8 af[4], bfr[4];
      #pragma unroll
      for(int mi=0;mi<4;mi++){
        int row = wm + mi*16 + (lane & 15);
        int ch = (ks*4 + (lane >> 4)) ^ (row & 7);
        af[mi] = *(const s16x8*)(&As[row*64 + ch*8]);
      }
      #pragma unroll
      for(int ni=0;ni<4;ni++){
        int row = wn + ni*16 + (lane & 15);
        int ch = (ks*4 + (lane >> 4)) ^ (row & 7);
        bfr[ni] = *(const s16x8*)(&Bs[row*64 + ch*8]);
      }
      #pragma unroll
      for(int mi=0;mi<4;mi++)
        #pragma unroll
        for(int ni=0;ni<4;ni++)
          acc[mi][ni] = __builtin_amdgcn_mfma_f32_16x16x32_bf16(af[mi], bfr[ni], acc[mi][ni], 0, 0, 0);
    }
    __syncthreads();
  }
  const int rb = (lane >> 4) * 4, cb = lane & 15;
  #pragma unroll
  for(int mi=0;mi<4;mi++){
    #pragma unroll
    for(int ni=0;ni<4;ni++){
      int col = n0 + wn + ni*16 + cb;
      int rowbase = m0 + wm + mi*16 + rb;
      if(EPI==6 && col >= 1024){
        // V columns: write transposed to vt[(b*8+h)*64+d][n] = vt[b*512+col-1024][n]
        u16x4 tv;
        #pragma unroll
        for(int r=0;r<4;r++) tv[r] = f2bf(acc[mi][ni][r]);
        int bb = rowbase >> 9, n = rowbase & 511;
        *(u16x4*)(vt + (((size_t)(bb*512 + col - 1024)) << 9) + n) = tv;
      } else {
        #pragma unroll
        for(int r=0;r<4;r++){
          int row = rowbase + r;
          float v = acc[mi][ni][r];
          if(EPI==1||EPI==2||EPI==4||EPI==5) v += bias[col];
          if(EPI==2) v = 0.5f*v + res[(size_t)row*N + col];
          if(EPI==3||EPI==5) v += res[(size_t)row*N + col];
          if(EPI==1) v = v * sigm(v);
          if(EPI==0||EPI==1||EPI==4||EPI==6) ((unsigned short*)outp)[(size_t)row*N + col] = f2bf(v);
          else                               ((float*)outp)[(size_t)row*N + col] = v;
        }
      }
    }
  }
}

// ---------------- GEMM 128x64 tile: for N=512 outputs (grid (8,64)=512 blocks) ----
// R10 analysis: (4,64)=256-block GEMMs ran at 1 block/CU = 12.5% occupancy.
// BN=64 doubles the grid -> 2 blocks/CU. 4 waves, each 32x64 (acc[2][4]); LDS 24KB.
template<int EPI>
__global__ __launch_bounds__(256, 2)
void k_gemm64(const unsigned short* __restrict__ A, const unsigned short* __restrict__ Bt,
              const float* __restrict__ bias, const float* __restrict__ res,
              void* __restrict__ outp, int M, int N, int K){
  __shared__ alignas(16) unsigned short As[128*64];
  __shared__ alignas(16) unsigned short Bs[64*64];
  const int tid = threadIdx.x, lane = tid & 63, wave = tid >> 6;
  const int nwg = gridDim.x * gridDim.y;
  int orig = blockIdx.x + gridDim.x * blockIdx.y;
  int q8 = nwg >> 3, r8 = nwg & 7, xcd = orig & 7, idx = orig >> 3;
  int wg = (xcd < r8 ? xcd * (q8 + 1) : r8 * (q8 + 1) + (xcd - r8) * q8) + idx;
  const int m0 = (wg / gridDim.x) * 128, n0 = (wg % gridDim.x) * 64;
  const int wm = wave * 32;
  f32x4 acc[2][4];
  #pragma unroll
  for(int a=0;a<2;a++)
    #pragma unroll
    for(int b=0;b<4;b++) acc[a][b] = (f32x4){0.f,0.f,0.f,0.f};

  for(int kt = 0; kt < K; kt += 64){
    #pragma unroll
    for(int i=0;i<4;i++){
      int flat = i*256 + tid;
      int r = flat >> 3;
      int cs = ((flat & 7) ^ (r & 7)) << 3;
      gload16(A + (size_t)(m0 + r)*K + kt + cs, &As[flat*8]);
    }
    #pragma unroll
    for(int i=0;i<2;i++){
      int flat = i*256 + tid;
      int r = flat >> 3;
      int cs = ((flat & 7) ^ (r & 7)) << 3;
      gload16(Bt + (size_t)(n0 + r)*K + kt + cs, &Bs[flat*8]);
    }
    __syncthreads();
    #pragma unroll
    for(int ks=0; ks<2; ks++){
      s16x8 af[2], bfr[4];
      #pragma unroll
      for(int mi=0;mi<2;mi++){
        int row = wm + mi*16 + (lane & 15);
        int ch = (ks*4 + (lane >> 4)) ^ (row & 7);
        af[mi] = *(const s16x8*)(&As[row*64 + ch*8]);
      }
      #pragma unroll
      for(int ni=0;ni<4;ni++){
        int row = ni*16 + (lane & 15);
        int ch = (ks*4 + (lane >> 4)) ^ (row & 7);
        bfr[ni] = *(const s16x8*)(&Bs[row*64 + ch*8]);
      }
      #pragma unroll
      for(int mi=0;mi<2;mi++)
        #pragma unroll
        for(int ni=0;ni<4;ni++)
          acc[mi][ni] = __builtin_amdgcn_mfma_f32_16x16x32_bf16(af[mi], bfr[ni], acc[mi][ni], 0, 0, 0);
    }
    __syncthreads();
  }
  const int rb = (lane >> 4) * 4, cb = lane & 15;
  #pragma unroll
  for(int mi=0;mi<2;mi++){
    #pragma unroll
    for(int ni=0;ni<4;ni++){
      int col = n0 + ni*16 + cb;
      int rowbase = m0 + wm + mi*16 + rb;
      #pragma unroll
      for(int r=0;r<4;r++){
        int row = rowbase + r;
        float v = acc[mi][ni][r];
        if(EPI==1||EPI==2||EPI==4||EPI==5) v += bias[col];
        if(EPI==2) v = 0.5f*v + res[(size_t)row*N + col];
        if(EPI==3||EPI==5) v += res[(size_t)row*N + col];
        if(EPI==1) v = v * sigm(v);
        if(EPI==0||EPI==1||EPI==4) ((unsigned short*)outp)[(size_t)row*N + col] = f2bf(v);
        else                        ((float*)outp)[(size_t)row*N + col] = v;
      }
    }
  }
}

// ---------------- fused attention, online softmax, LDS K (R9 config: 72.4us) ----
// grid (4 q-tiles of 128, H=8, B=16), 8 waves; wave w owns q rows n0w..n0w+15.
// Occupancy capped by GRID (4096 waves / 8192 slots), not LDS (R10 evidence).
// Per-lane global K reads are slower than ds_read even L2-resident (R10: +22us).
__global__ __launch_bounds__(512, 2)
void k_attn(const unsigned short* __restrict__ qkv, const unsigned short* __restrict__ vt,
            const unsigned short* __restrict__ emb, unsigned short* __restrict__ outb){
  __shared__ alignas(16) unsigned short Ks[512*64];   // K swizzled only
  const int tid = threadIdx.x, lane = tid & 63, w = tid >> 6;
  const int q0 = blockIdx.x * 128, h = blockIdx.y, b = blockIdx.z;
  const int j = lane & 15, g = lane >> 4;
  const int n0w = q0 + w*16;
  const size_t qkvbase = (size_t)b*N_*1536;

  // ---- stage K [512 r][64 ch]: linear dest, source chunk ^= r&7 ----
  #pragma unroll
  for(int i=0;i<8;i++){
    int flat = i*512 + tid;
    int r = flat >> 3;
    int cs = ((flat & 7) ^ (r & 7)) << 3;
    gload16(qkv + qkvbase + (size_t)r*1536 + 512 + h*64 + cs, &Ks[flat*8]);
  }
  // Q fragment: lane (j,g) holds Q[n0w+j][ks*32+g*8+e]
  s16x8 qf[2];
  #pragma unroll
  for(int ks=0;ks<2;ks++)
    qf[ks] = *(const s16x8*)(qkv + qkvbase + (size_t)(n0w + j)*1536 + h*64 + ks*32 + g*8);
  __syncthreads();

  const float C2 = 0.125f * 1.4426950408889634f;

  // band init: pa1 = Paux of virtual rt=-1 (rows n0w+513+j)
  f32x4 pa1 = {0.f,0.f,0.f,0.f};
  #pragma unroll
  for(int ks=0;ks<2;ks++){
    s16x8 e1 = *(const s16x8*)(emb + (size_t)(n0w + 513 + j)*64 + ks*32 + g*8);
    pa1 = __builtin_amdgcn_mfma_f32_16x16x32_bf16(e1, qf[ks], pa1, 0,0,0);
  }

  float m = -1e30f, l = 0.f;
  f32x4 o[4];
  #pragma unroll
  for(int dt=0;dt<4;dt++) o[dt] = (f32x4){0.f,0.f,0.f,0.f};
  const unsigned short* vbase = vt + (((size_t)(b*8 + h)) << 15);  // *64*512
  const int srcA = j + ((g & 1) << 5);
  const int srcB = srcA + 16;
  const bool hi = (g >= 2);

  #pragma unroll
  for(int rts=0; rts<16; rts++){
    f32x4 scs[2];
    #pragma unroll
    for(int sub=0; sub<2; sub++){
      const int rt = rts*2 + sub;
      const int cb = n0w - rt*16 + 512;
      f32x4 s   = {0.f,0.f,0.f,0.f};
      f32x4 pa0 = {0.f,0.f,0.f,0.f};
      #pragma unroll
      for(int ks=0;ks<2;ks++){
        int row = rt*16 + j;
        int ch = (ks*4 + g) ^ (row & 7);
        s16x8 kf = *(const s16x8*)(&Ks[row*64 + (ch<<3)]);
        s = __builtin_amdgcn_mfma_f32_16x16x32_bf16(kf, qf[ks], s, 0,0,0);
        s16x8 e0 = *(const s16x8*)(emb + (size_t)(cb - 15 + j)*64 + ks*32 + g*8);
        pa0 = __builtin_amdgcn_mfma_f32_16x16x32_bf16(e0, qf[ks], pa0, 0,0,0);
      }
      #pragma unroll
      for(int reg=0;reg<4;reg++){
        int elem = (j + 3 - reg) & 3;
        float s0 = (elem & 2) ? ((elem & 1) ? pa0[3] : pa0[2]) : ((elem & 1) ? pa0[1] : pa0[0]);
        float s1 = (elem & 2) ? ((elem & 1) ? pa1[3] : pa1[2]) : ((elem & 1) ? pa1[1] : pa1[0]);
        int mm = j + 15 - g*4 - reg;
        int src = j + (((mm & 15) >> 2) << 4);
        float v0 = __shfl(s0, src);
        float v1 = __shfl(s1, src);
        scs[sub][reg] = s[reg] + (mm < 16 ? v0 : v1);
      }
      pa1 = pa0;
    }
    float tmax = fmaxf(fmaxf(fmaxf(scs[0][0], scs[0][1]), fmaxf(scs[0][2], scs[0][3])),
                       fmaxf(fmaxf(scs[1][0], scs[1][1]), fmaxf(scs[1][2], scs[1][3])));
    tmax = fmaxf(tmax, __shfl_xor(tmax, 16));
    tmax = fmaxf(tmax, __shfl_xor(tmax, 32));
    if(__any(tmax > m + 48.f)){
      float mn = fmaxf(m, tmax);
      float f = exp2f((m - mn)*C2);
      l *= f;
      #pragma unroll
      for(int reg=0;reg<4;reg++){
        float fr = __shfl(f, (g<<2) + reg);
        #pragma unroll
        for(int dt=0;dt<4;dt++) o[dt][reg] *= fr;
      }
      m = mn;
    }
    const float mc = m * C2;
    unsigned wp[4];
    #pragma unroll
    for(int sub=0; sub<2; sub++){
      float p0 = exp2f(fmaf(scs[sub][0], C2, -mc));
      float p1 = exp2f(fmaf(scs[sub][1], C2, -mc));
      float p2 = exp2f(fmaf(scs[sub][2], C2, -mc));
      float p3 = exp2f(fmaf(scs[sub][3], C2, -mc));
      l += (p0 + p1) + (p2 + p3);
      wp[sub*2]   = cvtpk(p0, p1);
      wp[sub*2+1] = cvtpk(p2, p3);
    }
    // build PV A-frag via cross-lane gather of packed P
    unsigned a0 = __shfl(wp[0], srcA);
    unsigned a1 = __shfl(wp[1], srcA);
    unsigned a2 = __shfl(wp[0], srcB);
    unsigned a3 = __shfl(wp[1], srcB);
    unsigned b0 = __shfl(wp[2], srcA);
    unsigned b1 = __shfl(wp[3], srcA);
    unsigned b2 = __shfl(wp[2], srcB);
    unsigned b3 = __shfl(wp[3], srcB);
    union { unsigned u[4]; s16x8 v; } pu;
    pu.u[0] = hi ? b0 : a0;
    pu.u[1] = hi ? b1 : a1;
    pu.u[2] = hi ? b2 : a2;
    pu.u[3] = hi ? b3 : a3;
    #pragma unroll
    for(int dt=0;dt<4;dt++){
      int d = dt*16 + j;
      s16x8 vf = *(const s16x8*)(vbase + (size_t)d*512 + rts*32 + g*8);
      o[dt] = __builtin_amdgcn_mfma_f32_16x16x32_bf16(pu.v, vf, o[dt], 0,0,0);
    }
  }
  l += __shfl_xor(l, 16);
  l += __shfl_xor(l, 32);
  float inv = 1.f / l;
  #pragma unroll
  for(int reg=0;reg<4;reg++){
    float invq = __shfl(inv, (g<<2) + reg);
    int tok = n0w + (g<<2) + reg;
    #pragma unroll
    for(int dt=0;dt<4;dt++)
      outb[(size_t)(b*N_ + tok)*512 + h*64 + dt*16 + j] = f2bf(o[dt][reg] * invq);
  }
}

// ---------------- GLU ----------------
__global__ void k_glu(const unsigned short* __restrict__ hid, unsigned short* __restrict__ outp){
  size_t i = (size_t)blockIdx.x*256 + threadIdx.x;   // chunk of 8
  int row = (int)(i >> 7), cc = (int)(i & 127);
  u16x8 a  = *(const u16x8*)(hid + (size_t)row*2048 + cc*8);
  u16x8 gt = *(const u16x8*)(hid + (size_t)row*2048 + 1024 + cc*8);
  u16x8 o;
  #pragma unroll
  for(int e=0;e<8;e++){
    float av = bf2f(a[e]), gv = bf2f(gt[e]);
    o[e] = f2bf(av * sigm(gv));
  }
  *(u16x8*)(outp + (size_t)row*1024 + cc*8) = o;
}

// ---------------- depthwise conv 31 + BN + swish ----------------
__global__ __launch_bounds__(256, 2)
void k_dwconv(const unsigned short* __restrict__ gin, const float* __restrict__ dww,
              const float* __restrict__ dwb, const float* __restrict__ bng,
              const float* __restrict__ bnb, const float* __restrict__ bnm,
              const float* __restrict__ bnv, unsigned short* __restrict__ outp){
  __shared__ unsigned short gl[94][136];
  __shared__ float wl[31][128];
  const int c0 = blockIdx.x*128, n0 = blockIdx.y*64, b = blockIdx.z;
  const int tid = threadIdx.x;
  for(int i=0;i<6;i++){
    int flat = i*256 + tid;
    if(flat < 94*16){
      int r = flat >> 4, c = flat & 15;
      int n = n0 - 15 + r;
      u16x8 v = {0,0,0,0,0,0,0,0};
      if(n >= 0 && n < 512) v = *(const u16x8*)(gin + (size_t)(b*512 + n)*1024 + c0 + c*8);
      *(u16x8*)(&gl[r][c*8]) = v;
    }
  }
  for(int i=0;i<16;i++){
    int flat = i*256 + tid;
    if(flat < 31*128){
      int t = flat >> 7, cc = flat & 127;
      wl[t][cc] = dww[(size_t)(c0 + cc)*31 + t];
    }
  }
  __syncthreads();
  const int tc = tid & 31, tn = tid >> 5;
  f32x4 acc[8];
  #pragma unroll
  for(int nn=0;nn<8;nn++) acc[nn] = (f32x4){0.f,0.f,0.f,0.f};
  for(int t=0;t<31;t++){
    f32x4 wv = *(const f32x4*)(&wl[t][tc*4]);
    #pragma unroll
    for(int nn=0;nn<8;nn++){
      s16x4 gv = *(const s16x4*)(&gl[tn*8 + nn + t][tc*4]);
      f32x4 g4 = { bf2f((unsigned short)gv[0]), bf2f((unsigned short)gv[1]),
                   bf2f((unsigned short)gv[2]), bf2f((unsigned short)gv[3]) };
      acc[nn] += g4 * wv;
    }
  }
  #pragma unroll
  for(int e=0;e<4;e++){
    int c = c0 + tc*4 + e;
    float s  = bng[c] * rsqrtf(bnv[c] + 1e-5f);
    float sh = bnb[c] - bnm[c]*s;
    float db = dwb[c];
    #pragma unroll
    for(int nn=0;nn<8;nn++){
      float v = (acc[nn][e] + db)*s + sh;
      v = v * sigm(v);
      outp[(size_t)(b*512 + n0 + tn*8 + nn)*1024 + c] = f2bf(v);
    }
  }
}

// ---------------- launch ----------------
extern "C" void kernel_launch(void* const* d_in, const int* in_sizes, int n_in,
                              void* d_out, int out_size, void* d_ws, size_t ws_size,
                              hipStream_t stream){
  const float* x        = (const float*)d_in[0];
  const float* ff1_ln_g = (const float*)d_in[1];
  const float* ff1_ln_b = (const float*)d_in[2];
  const float* ff1_w1   = (const float*)d_in[3];
  const float* ff1_b1   = (const float*)d_in[4];
  const float* ff1_w2   = (const float*)d_in[5];
  const float* ff1_b2   = (const float*)d_in[6];
  const float* attn_ln_g= (const float*)d_in[7];
  const float* attn_ln_b= (const float*)d_in[8];
  const float* qkv_w    = (const float*)d_in[9];
  const float* out_w    = (const float*)d_in[10];
  const float* rel_emb  = (const float*)d_in[11];
  const float* conv_ln_g= (const float*)d_in[12];
  const float* conv_ln_b= (const float*)d_in[13];
  const float* pw1_w    = (const float*)d_in[14];
  const float* pw1_b    = (const float*)d_in[15];
  const float* dw_w     = (const float*)d_in[16];
  const float* dw_b     = (const float*)d_in[17];
  const float* bn_g     = (const float*)d_in[18];
  const float* bn_b     = (const float*)d_in[19];
  const float* bn_mean  = (const float*)d_in[20];
  const float* bn_var   = (const float*)d_in[21];
  const float* pw2_w    = (const float*)d_in[22];
  const float* pw2_b    = (const float*)d_in[23];
  const float* ff2_ln_g = (const float*)d_in[24];
  const float* ff2_ln_b = (const float*)d_in[25];
  const float* ff2_w1   = (const float*)d_in[26];
  const float* ff2_b1   = (const float*)d_in[27];
  const float* ff2_w2   = (const float*)d_in[28];
  const float* ff2_b2   = (const float*)d_in[29];
  const float* post_ln_g= (const float*)d_in[30];
  const float* post_ln_b= (const float*)d_in[31];
  (void)in_sizes; (void)n_in; (void)out_size; (void)ws_size;

  char* ws = (char*)d_ws;
  size_t off = 0;
  auto alloc = [&](size_t bytes)->char*{ char* p = ws + off; off += (bytes + 255) & ~(size_t)255; return p; };
  float*          res  = (float*)         alloc((size_t)ROWS*512*4);
  unsigned short* hbuf = (unsigned short*)alloc((size_t)ROWS*512*2);
  unsigned short* hid  = (unsigned short*)alloc((size_t)ROWS*2048*2);
  unsigned short* qkvb = (unsigned short*)alloc((size_t)ROWS*1536*2);
  unsigned short* glub = (unsigned short*)alloc((size_t)ROWS*1024*2);
  unsigned short* attnout = glub;   // alias: attn_out consumed before GLU is written
  unsigned short* dwout   = qkvb;   // alias: qkv consumed before dwconv output written
  unsigned short* vtb     = hid;    // alias: hid free between FF1 and conv module
  unsigned short* w1t  = (unsigned short*)alloc((size_t)2048*512*2);
  unsigned short* w2t  = (unsigned short*)alloc((size_t)2048*512*2);
  unsigned short* qkvt = (unsigned short*)alloc((size_t)1536*512*2);
  unsigned short* outt = (unsigned short*)alloc((size_t)512*512*2);
  unsigned short* pw1c = (unsigned short*)alloc((size_t)2048*512*2);
  unsigned short* pw2c = (unsigned short*)alloc((size_t)512*1024*2);
  unsigned short* f2w1t= (unsigned short*)alloc((size_t)2048*512*2);
  unsigned short* f2w2t= (unsigned short*)alloc((size_t)2048*512*2);
  unsigned short* rele = (unsigned short*)alloc((size_t)1025*64*2);

  // weight prep (all -> bf16 [N][K])
  k_transpose_cvt<<<dim3(64, 16), 256, 0, stream>>>(ff1_w1, w1t, 512, 2048);
  k_transpose_cvt<<<dim3(16, 64), 256, 0, stream>>>(ff1_w2, w2t, 2048, 512);
  k_transpose_cvt<<<dim3(48, 16), 256, 0, stream>>>(qkv_w, qkvt, 512, 1536);
  k_transpose_cvt<<<dim3(16, 16), 256, 0, stream>>>(out_w, outt, 512, 512);
  k_transpose_cvt<<<dim3(64, 16), 256, 0, stream>>>(ff2_w1, f2w1t, 512, 2048);
  k_transpose_cvt<<<dim3(16, 64), 256, 0, stream>>>(ff2_w2, f2w2t, 2048, 512);
  k_cvt<<<2048*512/256, 256, 0, stream>>>(pw1_w, pw1c, 2048*512);
  k_cvt<<<512*1024/256, 256, 0, stream>>>(pw2_w, pw2c, 512*1024);
  k_cvt<<<(1025*64+255)/256, 256, 0, stream>>>(rel_emb, rele, 1025*64);

  // FF1 (x + 0.5*ff(x))
  k_ln<0><<<ROWS/4, 256, 0, stream>>>(x, ff1_ln_g, ff1_ln_b, hbuf);
  k_gemm<1><<<dim3(16, 64), 256, 0, stream>>>(hbuf, w1t, ff1_b1, nullptr, hid, nullptr, ROWS, 2048, 512);
  k_gemm64<2><<<dim3(8, 64), 256, 0, stream>>>(hid, w2t, ff1_b2, x, res, ROWS, 512, 2048);
  // attention
  k_ln<0><<<ROWS/4, 256, 0, stream>>>(res, attn_ln_g, attn_ln_b, hbuf);
  k_gemm<6><<<dim3(12, 64), 256, 0, stream>>>(hbuf, qkvt, nullptr, nullptr, qkvb, vtb, ROWS, 1536, 512);
  k_attn<<<dim3(4, 8, 16), 512, 0, stream>>>(qkvb, vtb, rele, attnout);
  k_gemm64<3><<<dim3(8, 64), 256, 0, stream>>>(attnout, outt, nullptr, res, res, ROWS, 512, 512);
  // conv module
  k_ln<0><<<ROWS/4, 256, 0, stream>>>(res, conv_ln_g, conv_ln_b, hbuf);
  k_gemm<4><<<dim3(16, 64), 256, 0, stream>>>(hbuf, pw1c, pw1_b, nullptr, hid, nullptr, ROWS, 2048, 512);
  k_glu<<<ROWS*128/256, 256, 0, stream>>>(hid, glub);
  k_dwconv<<<dim3(8, 8, 16), 256, 0, stream>>>(glub, dw_w, dw_b, bn_g, bn_b, bn_mean, bn_var, dwout);
  k_gemm64<5><<<dim3(8, 64), 256, 0, stream>>>(dwout, pw2c, pw2_b, res, res, ROWS, 512, 1024);
  // FF2
  k_ln<0><<<ROWS/4, 256, 0, stream>>>(res, ff2_ln_g, ff2_ln_b, hbuf);
  k_gemm<1><<<dim3(16, 64), 256, 0, stream>>>(hbuf, f2w1t, ff2_b1, nullptr, hid, nullptr, ROWS, 2048, 512);
  k_gemm64<2><<<dim3(8, 64), 256, 0, stream>>>(hid, f2w2t, ff2_b2, res, res, ROWS, 512, 2048);
  // post-norm -> fp32 output
  k_ln<1><<<ROWS/4, 256, 0, stream>>>(res, post_ln_g, post_ln_b, d_out);
}